// Round 6
// baseline (646.730 us; speedup 1.0000x reference)
//
#include <hip/hip_runtime.h>
#include <math.h>

// Problem constants
#define DD   16     // model dim
#define NH   8      // heads (head dim = 2)
#define NL   8      // layers
#define FFD  16     // ff dim
#define KK   35     // conv kernel / patch size
#define SEQ  3500   // input seq
#define NP   100    // patches
#define SS   101    // tokens (cls + patches)
#define NBATCH 2    // batches per block; batch slot = wave>>1 (wave-uniform)
#define NT   256    // 4 waves; grid = 1024 = 4 blocks/CU, 16 waves/CU
#define ROWB 64     // bytes per kv row in ws (K fp16 8dw | V fp16 8dw)
#define BATB (SS * ROWB)            // 6464 B per batch
#define NWPAIR 6144                 // packed weight half2 count (24.6 KB)

typedef __fp16 h2 __attribute__((ext_vector_type(2)));
typedef int  v16i __attribute__((ext_vector_type(16)));

__device__ __forceinline__ float fdot2(h2 a, h2 b, float c) {
#if __has_builtin(__builtin_amdgcn_fdot2)
  return __builtin_amdgcn_fdot2(a, b, c, false);
#else
  return c + (float)a.x * (float)b.x + (float)a.y * (float)b.y;
#endif
}
__device__ __forceinline__ float exp2_fast(float x) {
#if __has_builtin(__builtin_amdgcn_exp2f)
  return __builtin_amdgcn_exp2f(x);
#else
  return exp2f(x);
#endif
}
__device__ __forceinline__ float rcp_fast(float x) {
#if __has_builtin(__builtin_amdgcn_rcpf)
  return __builtin_amdgcn_rcpf(x);
#else
  return 1.0f / x;
#endif
}
__device__ __forceinline__ h2 pk_h2(float a, float b) {
#if __has_builtin(__builtin_amdgcn_cvt_pkrtz)
  return __builtin_amdgcn_cvt_pkrtz(a, b);
#else
  h2 r; r.x = (__fp16)a; r.y = (__fp16)b; return r;
#endif
}
__device__ __forceinline__ unsigned pk_u(float a, float b) {
  return __builtin_bit_cast(unsigned, pk_h2(a, b));
}
__device__ __forceinline__ h2 as_h2(unsigned u) {
  return __builtin_bit_cast(h2, u);
}

__device__ __forceinline__ void lnorm16(float* h, const float* __restrict__ g,
                                        const float* __restrict__ bb) {
  float mu = 0.f;
  #pragma unroll
  for (int d = 0; d < DD; ++d) mu += h[d];
  mu *= (1.f / DD);
  float var = 0.f;
  #pragma unroll
  for (int d = 0; d < DD; ++d) { float c = h[d] - mu; var += c * c; }
  var *= (1.f / DD);
  const float r = rsqrtf(var + 1e-5f);
  #pragma unroll
  for (int d = 0; d < DD; ++d) h[d] = (h[d] - mu) * r * g[d] + bb[d];
}

// 16-dim dot via 8 x v_dot2_f32_f16 (weights pre-packed as half2)
__device__ __forceinline__ float dot16(const h2* hv, const unsigned* __restrict__ w, float acc) {
  #pragma unroll
  for (int i = 0; i < 8; ++i) acc = fdot2(hv[i], as_h2(w[i]), acc);
  return acc;
}

// ---- prep: pack [Wqkv|Wo|W1|W2] f32 pairs into half2 ----
__global__ __launch_bounds__(256)
void pack_weights(const float* __restrict__ Wqkv, const float* __restrict__ Wo,
                  const float* __restrict__ W1,   const float* __restrict__ W2,
                  unsigned* __restrict__ dst)
{
  const int i = blockIdx.x * 256 + threadIdx.x;
  if (i >= NWPAIR) return;
  float a, b;
  if (i < 3072)      { a = Wqkv[2*i];        b = Wqkv[2*i+1]; }
  else if (i < 4096) { int j = i - 3072; a = Wo[2*j]; b = Wo[2*j+1]; }
  else if (i < 5120) { int j = i - 4096; a = W1[2*j]; b = W1[2*j+1]; }
  else               { int j = i - 5120; a = W2[2*j]; b = W2[2*j+1]; }
  dst[i] = pk_u(a, b);
}

// ---------------- primary: kv in global, read via scalar loads (SMEM pipe) ----
__global__ __launch_bounds__(NT, 4)
void transformer_fwd_s(const float* __restrict__ x,
                       const float* __restrict__ conv_w,  const float* __restrict__ conv_b,
                       const float* __restrict__ cls_emb,
                       const float* __restrict__ bqkv,
                       const float* __restrict__ bo,
                       const float* __restrict__ b1,
                       const float* __restrict__ b2,
                       const float* __restrict__ ln1_g,   const float* __restrict__ ln1_b,
                       const float* __restrict__ ln2_g,   const float* __restrict__ ln2_b,
                       const float* __restrict__ lnf_g,   const float* __restrict__ lnf_b,
                       const float* __restrict__ end_w,   const float* __restrict__ end_b,
                       const float* __restrict__ head_w,  const float* __restrict__ head_b,
                       float* __restrict__ out, char* __restrict__ ws,
                       const unsigned* __restrict__ wpk, int B)
{
  __shared__ float s_cls[NBATCH][DD];
  __shared__ float s_lat[NBATCH][NP];

  const int tid  = threadIdx.x;
  const int wid  = tid >> 6;
  const int lane = tid & 63;
  const int j    = wid >> 1;                // wave-uniform batch slot
  const int r    = ((wid & 1) << 6) + lane; // row 0..127
  const int b    = blockIdx.x * NBATCH + j;
  const bool act = (r < SS) && (b < B);

  // uniform kv base for scalar loads; per-lane ptr for stores (same value)
  const int   b_u    = __builtin_amdgcn_readfirstlane(b);
  const char* kvbase = ws + (size_t)b_u * BATB;
  uint4*      kvw    = (uint4*)(ws + (size_t)b * BATB);

  // ---- conv patch embed (idle lanes: h = 0, kept finite everywhere) ----
  float h[DD];
  #pragma unroll
  for (int d = 0; d < DD; ++d) h[d] = 0.f;
  if (act) {
    if (r == 0) {
      #pragma unroll
      for (int d = 0; d < DD; ++d) h[d] = cls_emb[d];
    } else {
      const float* xp = x + (size_t)b * SEQ + (r - 1) * KK;
      float xv[KK];
      #pragma unroll
      for (int k = 0; k < KK; ++k) xv[k] = xp[k];
      #pragma unroll
      for (int f = 0; f < DD; ++f) {
        float acc = conv_b[f];
        #pragma unroll
        for (int k = 0; k < KK; ++k) acc += xv[k] * conv_w[f * KK + k];
        h[f] = acc;
      }
    }
  }

  const float qs = 1.4426950408889634f * 0.70710678118654752f; // log2e / sqrt(2)

  for (int l = 0; l < NL; ++l) {
    const unsigned* wq16 = wpk + l * 384;
    const unsigned* wo16 = wpk + 3072 + l * 128;
    const unsigned* w116 = wpk + 4096 + l * 128;
    const unsigned* w216 = wpk + 5120 + l * 128;
    const float* bq  = bqkv + l * (3 * DD);
    const float* bol = bo   + l * DD;
    const float* b1l = b1   + l * FFD;
    const float* b2l = b2   + l * DD;
    const float* g1  = ln1_g + l * DD;  const float* be1 = ln1_b + l * DD;
    const float* g2  = ln2_g + l * DD;  const float* be2 = ln2_b + l * DD;

    __syncthreads();   // all reads of kv region (prev layer) complete

    // ---- projections (uniform control flow; idle lanes compute on zeros) ----
    h2 hv[8];
    #pragma unroll
    for (int i = 0; i < 8; ++i) hv[i] = pk_h2(h[2*i], h[2*i+1]);

    h2 q2[NH];
    #pragma unroll
    for (int hh = 0; hh < NH; ++hh) {
      const float a0 = dot16(hv, &wq16[(2*hh    ) * 8], bq[2*hh]);
      const float a1 = dot16(hv, &wq16[(2*hh + 1) * 8], bq[2*hh+1]);
      q2[hh] = pk_h2(a0 * qs, a1 * qs);
    }
    unsigned row[16];
    #pragma unroll
    for (int e = 0; e < 16; e += 2) {  // k
      const float a0 = dot16(hv, &wq16[(DD + e    ) * 8], bq[DD + e]);
      const float a1 = dot16(hv, &wq16[(DD + e + 1) * 8], bq[DD + e + 1]);
      row[e >> 1] = pk_u(a0, a1);
    }
    #pragma unroll
    for (int e = 0; e < 16; e += 2) {  // v
      const float a0 = dot16(hv, &wq16[(2*DD + e    ) * 8], bq[2*DD + e]);
      const float a1 = dot16(hv, &wq16[(2*DD + e + 1) * 8], bq[2*DD + e + 1]);
      row[8 + (e >> 1)] = pk_u(a0, a1);
    }
    if (act) {
      uint4* dst = kvw + (size_t)r * 4;   // 64 B/row
      dst[0] = make_uint4(row[0],  row[1],  row[2],  row[3]);
      dst[1] = make_uint4(row[4],  row[5],  row[6],  row[7]);
      dst[2] = make_uint4(row[8],  row[9],  row[10], row[11]);
      dst[3] = make_uint4(row[12], row[13], row[14], row[15]);
    }
    __syncthreads();   // kv in L2 (vector L1 is write-through; vmcnt drained)

    // scalar L1 may hold stale lines from the previous layer's reads
    asm volatile("s_dcache_inv" ::: "memory");

    // ---- attention t-loop: one s_load_dwordx16 per row, math from SGPRs ----
    float lsum[NH], cxx[NH], cxy[NH];
    #pragma unroll
    for (int hh = 0; hh < NH; ++hh) { lsum[hh] = 0.f; cxx[hh] = 0.f; cxy[hh] = 0.f; }

    #pragma unroll 2
    for (int t = 0; t < SS; ++t) {
      v16i kv;
      const char* ap = kvbase + (size_t)t * ROWB;
      asm volatile("s_load_dwordx16 %0, %1, 0x0\n\t"
                   "s_waitcnt lgkmcnt(0)"
                   : "=s"(kv) : "s"(ap) : "memory");
      #pragma unroll
      for (int hh = 0; hh < NH; ++hh) {
        const h2 kk = as_h2((unsigned)kv[hh]);
        const h2 vv = as_h2((unsigned)kv[8 + hh]);
        const float p = exp2_fast(fdot2(q2[hh], kk, 0.0f));
        lsum[hh] += p;
        cxx[hh]  += (float)vv.x * p;   // v_fma_mix, V operand from SGPR
        cxy[hh]  += (float)vv.y * p;
      }
    }

    float cx[DD];
    #pragma unroll
    for (int hh = 0; hh < NH; ++hh) {
      const float inv = rcp_fast(lsum[hh]);
      cx[2 * hh]     = cxx[hh] * inv;
      cx[2 * hh + 1] = cxy[hh] * inv;
    }

    // ---- Wo + residual + LN1 ----
    h2 cv[8];
    #pragma unroll
    for (int i = 0; i < 8; ++i) cv[i] = pk_h2(cx[2*i], cx[2*i+1]);
    #pragma unroll
    for (int od = 0; od < DD; ++od)
      h[od] += dot16(cv, &wo16[od * 8], bol[od]);
    lnorm16(h, g1, be1);

    // ---- FF + residual + LN2 ----
    h2 hv2[8];
    #pragma unroll
    for (int i = 0; i < 8; ++i) hv2[i] = pk_h2(h[2*i], h[2*i+1]);
    float fv[FFD];
    #pragma unroll
    for (int f = 0; f < FFD; ++f)
      fv[f] = fmaxf(dot16(hv2, &w116[f * 8], b1l[f]), 0.f);
    h2 fv2[8];
    #pragma unroll
    for (int i = 0; i < 8; ++i) fv2[i] = pk_h2(fv[2*i], fv[2*i+1]);
    #pragma unroll
    for (int od = 0; od < DD; ++od)
      h[od] += dot16(fv2, &w216[od * 8], b2l[od]);
    lnorm16(h, g2, be2);
  }

  // ---- final LN (cls rows) + head ----
  __syncthreads();
  if (act && r == 0) {
    lnorm16(h, lnf_g, lnf_b);
    #pragma unroll
    for (int d = 0; d < DD; ++d) s_cls[j][d] = h[d];
  }
  __syncthreads();
  if (tid < NBATCH * NP) {
    const int jj = tid / NP;
    const int oo = tid - jj * NP;
    if (blockIdx.x * NBATCH + jj < B) {
      float acc = end_b[oo];
      #pragma unroll
      for (int d = 0; d < DD; ++d) acc += s_cls[jj][d] * end_w[oo * DD + d];
      s_lat[jj][oo] = acc * head_w[oo];
    }
  }
  __syncthreads();
  if (tid < NBATCH) {
    const int bb = blockIdx.x * NBATCH + tid;
    if (bb < B) {
      float acc = head_b[0];
      for (int o = 0; o < NP; ++o) acc += s_lat[tid][o];
      out[bb] = rcp_fast(1.f + exp2_fast(-acc * 1.4426950408889634f));
    }
  }
}

// ---------------- fallback: R5 kernel (kv in LDS, needs only 24KB ws) --------
#define ROWDW 20
#define NROW 102

__global__ __launch_bounds__(NT, 4)
void transformer_fwd_g(const float* __restrict__ x,
                       const float* __restrict__ conv_w,  const float* __restrict__ conv_b,
                       const float* __restrict__ cls_emb,
                       const float* __restrict__ bqkv,
                       const float* __restrict__ bo,
                       const float* __restrict__ b1,
                       const float* __restrict__ b2,
                       const float* __restrict__ ln1_g,   const float* __restrict__ ln1_b,
                       const float* __restrict__ ln2_g,   const float* __restrict__ ln2_b,
                       const float* __restrict__ lnf_g,   const float* __restrict__ lnf_b,
                       const float* __restrict__ end_w,   const float* __restrict__ end_b,
                       const float* __restrict__ head_w,  const float* __restrict__ head_b,
                       float* __restrict__ out,
                       const unsigned* __restrict__ wpk, int B)
{
  __shared__ unsigned s_kv[NBATCH][NROW * ROWDW];
  __shared__ float s_cls[NBATCH][DD];
  __shared__ float s_lat[NBATCH][NP];

  const int tid  = threadIdx.x;
  const int wid  = tid >> 6;
  const int lane = tid & 63;
  const int j    = wid >> 1;
  const int r    = ((wid & 1) << 6) + lane;
  const int b    = blockIdx.x * NBATCH + j;
  const bool act = (r < SS) && (b < B);

  float h[DD];
  if (act) {
    if (r == 0) {
      #pragma unroll
      for (int d = 0; d < DD; ++d) h[d] = cls_emb[d];
    } else {
      const float* xp = x + (size_t)b * SEQ + (r - 1) * KK;
      float xv[KK];
      #pragma unroll
      for (int k = 0; k < KK; ++k) xv[k] = xp[k];
      #pragma unroll
      for (int f = 0; f < DD; ++f) {
        float acc = conv_b[f];
        #pragma unroll
        for (int k = 0; k < KK; ++k) acc += xv[k] * conv_w[f * KK + k];
        h[f] = acc;
      }
    }
  }

  const float qs = 1.4426950408889634f * 0.70710678118654752f;

  for (int l = 0; l < NL; ++l) {
    const unsigned* wq16 = wpk + l * 384;
    const unsigned* wo16 = wpk + 3072 + l * 128;
    const unsigned* w116 = wpk + 4096 + l * 128;
    const unsigned* w216 = wpk + 5120 + l * 128;
    const float* bq  = bqkv + l * (3 * DD);
    const float* bol = bo   + l * DD;
    const float* b1l = b1   + l * FFD;
    const float* b2l = b2   + l * DD;
    const float* g1  = ln1_g + l * DD;  const float* be1 = ln1_b + l * DD;
    const float* g2  = ln2_g + l * DD;  const float* be2 = ln2_b + l * DD;

    __syncthreads();

    h2 q2[NH];
    if (act) {
      h2 hv[8];
      #pragma unroll
      for (int i = 0; i < 8; ++i) hv[i] = pk_h2(h[2*i], h[2*i+1]);
      #pragma unroll
      for (int hh = 0; hh < NH; ++hh) {
        const float a0 = dot16(hv, &wq16[(2*hh    ) * 8], bq[2*hh]);
        const float a1 = dot16(hv, &wq16[(2*hh + 1) * 8], bq[2*hh+1]);
        q2[hh] = pk_h2(a0 * qs, a1 * qs);
      }
      unsigned row[16];
      #pragma unroll
      for (int e = 0; e < 16; e += 2) {
        const float a0 = dot16(hv, &wq16[(DD + e    ) * 8], bq[DD + e]);
        const float a1 = dot16(hv, &wq16[(DD + e + 1) * 8], bq[DD + e + 1]);
        row[e >> 1] = pk_u(a0, a1);
      }
      #pragma unroll
      for (int e = 0; e < 16; e += 2) {
        const float a0 = dot16(hv, &wq16[(2*DD + e    ) * 8], bq[2*DD + e]);
        const float a1 = dot16(hv, &wq16[(2*DD + e + 1) * 8], bq[2*DD + e + 1]);
        row[8 + (e >> 1)] = pk_u(a0, a1);
      }
      uint4* dst = (uint4*)&s_kv[j][r * ROWDW];
      dst[0] = make_uint4(row[0],  row[1],  row[2],  row[3]);
      dst[1] = make_uint4(row[4],  row[5],  row[6],  row[7]);
      dst[2] = make_uint4(row[8],  row[9],  row[10], row[11]);
      dst[3] = make_uint4(row[12], row[13], row[14], row[15]);
    }
    __syncthreads();

    if (act) {
      float lsum[NH], cxx[NH], cxy[NH];
      #pragma unroll
      for (int hh = 0; hh < NH; ++hh) { lsum[hh] = 0.f; cxx[hh] = 0.f; cxy[hh] = 0.f; }
      const uint4* kv = (const uint4*)&s_kv[j][0];
      uint4 c0 = kv[0], c1 = kv[1], c2 = kv[2], c3 = kv[3];
      #pragma unroll 2
      for (int t = 0; t < SS; ++t) {
        const uint4* np = kv + 5 * (t + 1);
        const uint4 n0 = np[0], n1 = np[1], n2 = np[2], n3 = np[3];
        const unsigned ku[8] = {c0.x, c0.y, c0.z, c0.w, c1.x, c1.y, c1.z, c1.w};
        const unsigned vu[8] = {c2.x, c2.y, c2.z, c2.w, c3.x, c3.y, c3.z, c3.w};
        #pragma unroll
        for (int hh = 0; hh < NH; ++hh) {
          const h2 kk = as_h2(ku[hh]);
          const h2 vv = as_h2(vu[hh]);
          const float p = exp2_fast(fdot2(q2[hh], kk, 0.0f));
          lsum[hh] += p;
          cxx[hh]  += (float)vv.x * p;
          cxy[hh]  += (float)vv.y * p;
        }
        c0 = n0; c1 = n1; c2 = n2; c3 = n3;
      }
      float cx[DD];
      #pragma unroll
      for (int hh = 0; hh < NH; ++hh) {
        const float inv = rcp_fast(lsum[hh]);
        cx[2 * hh]     = cxx[hh] * inv;
        cx[2 * hh + 1] = cxy[hh] * inv;
      }
      h2 cv[8];
      #pragma unroll
      for (int i = 0; i < 8; ++i) cv[i] = pk_h2(cx[2*i], cx[2*i+1]);
      #pragma unroll
      for (int od = 0; od < DD; ++od)
        h[od] += dot16(cv, &wo16[od * 8], bol[od]);
      lnorm16(h, g1, be1);
      h2 hv2[8];
      #pragma unroll
      for (int i = 0; i < 8; ++i) hv2[i] = pk_h2(h[2*i], h[2*i+1]);
      float fv[FFD];
      #pragma unroll
      for (int f = 0; f < FFD; ++f)
        fv[f] = fmaxf(dot16(hv2, &w116[f * 8], b1l[f]), 0.f);
      h2 fv2[8];
      #pragma unroll
      for (int i = 0; i < 8; ++i) fv2[i] = pk_h2(fv[2*i], fv[2*i+1]);
      #pragma unroll
      for (int od = 0; od < DD; ++od)
        h[od] += dot16(fv2, &w216[od * 8], b2l[od]);
      lnorm16(h, g2, be2);
    }
  }

  __syncthreads();
  if (act && r == 0) {
    lnorm16(h, lnf_g, lnf_b);
    #pragma unroll
    for (int d = 0; d < DD; ++d) s_cls[j][d] = h[d];
  }
  __syncthreads();
  if (tid < NBATCH * NP) {
    const int jj = tid / NP;
    const int oo = tid - jj * NP;
    if (blockIdx.x * NBATCH + jj < B) {
      float acc = end_b[oo];
      #pragma unroll
      for (int d = 0; d < DD; ++d) acc += s_cls[jj][d] * end_w[oo * DD + d];
      s_lat[jj][oo] = acc * head_w[oo];
    }
  }
  __syncthreads();
  if (tid < NBATCH) {
    const int bb = blockIdx.x * NBATCH + tid;
    if (bb < B) {
      float acc = head_b[0];
      for (int o = 0; o < NP; ++o) acc += s_lat[tid][o];
      out[bb] = rcp_fast(1.f + exp2_fast(-acc * 1.4426950408889634f));
    }
  }
}

extern "C" void kernel_launch(void* const* d_in, const int* in_sizes, int n_in,
                              void* d_out, int out_size, void* d_ws, size_t ws_size,
                              hipStream_t stream) {
  const float* x       = (const float*)d_in[0];
  const float* conv_w  = (const float*)d_in[1];
  const float* conv_b  = (const float*)d_in[2];
  const float* cls_emb = (const float*)d_in[3];
  const float* Wqkv    = (const float*)d_in[4];
  const float* bqkv    = (const float*)d_in[5];
  const float* Wo      = (const float*)d_in[6];
  const float* bo      = (const float*)d_in[7];
  const float* W1      = (const float*)d_in[8];
  const float* b1      = (const float*)d_in[9];
  const float* W2      = (const float*)d_in[10];
  const float* b2      = (const float*)d_in[11];
  const float* ln1_g   = (const float*)d_in[12];
  const float* ln1_b   = (const float*)d_in[13];
  const float* ln2_g   = (const float*)d_in[14];
  const float* ln2_b   = (const float*)d_in[15];
  const float* lnf_g   = (const float*)d_in[16];
  const float* lnf_b   = (const float*)d_in[17];
  const float* end_w   = (const float*)d_in[18];
  const float* end_b   = (const float*)d_in[19];
  const float* head_w  = (const float*)d_in[20];
  const float* head_b  = (const float*)d_in[21];
  float* out = (float*)d_out;

  const int B = in_sizes[0] / SEQ;   // 2048
  const size_t kv_bytes = (size_t)B * BATB;          // 13.24 MB
  const int nb = (B + NBATCH - 1) / NBATCH;          // 1024

  if (ws_size >= kv_bytes + NWPAIR * sizeof(unsigned)) {
    unsigned* wpk = (unsigned*)((char*)d_ws + kv_bytes);
    pack_weights<<<(NWPAIR + 255) / 256, 256, 0, stream>>>(Wqkv, Wo, W1, W2, wpk);
    transformer_fwd_s<<<nb, NT, 0, stream>>>(
        x, conv_w, conv_b, cls_emb, bqkv, bo, b1, b2,
        ln1_g, ln1_b, ln2_g, ln2_b, lnf_g, lnf_b, end_w, end_b, head_w, head_b,
        out, (char*)d_ws, wpk, B);
  } else {
    unsigned* wpk = (unsigned*)d_ws;
    pack_weights<<<(NWPAIR + 255) / 256, 256, 0, stream>>>(Wqkv, Wo, W1, W2, wpk);
    transformer_fwd_g<<<nb, NT, 0, stream>>>(
        x, conv_w, conv_b, cls_emb, bqkv, bo, b1, b2,
        ln1_g, ln1_b, ln2_g, ln2_b, lnf_g, lnf_b, end_w, end_b, head_w, head_b,
        out, wpk, B);
  }
}